// Round 9
// baseline (119.856 us; speedup 1.0000x reference)
//
#include <hip/hip_runtime.h>
#include <math.h>

#define MU_MAXC 32
#define MV_MAXC 32
#define OUT_UC  64
#define OUT_VC  64
#define DEG     3
#define NKNOT   (MU_MAXC + DEG + 1)   // 36
#define EPSV    1e-5f

__global__ void zero_ws_kernel(double* acc, int* bad) {
    acc[0] = 0.0; acc[1] = 0.0; acc[2] = 0.0; bad[0] = 0;
}

// Clamped open-uniform knot value (padded k >= L-1-DEG clamps to 1.0).
__device__ __forceinline__ float kv_at(int k, int L) {
    return (k <= DEG) ? 0.f : ((k >= L - 1 - DEG) ? 1.f : (float)k / (float)(L - 1));
}

// Half-sample blocks (grid 2*Bcnt): sample s=bb>>1, u-rows [32h,32h+32).
// Block start bulk-issues its 24 KB xyz half-tile to LDS via
// global_load_lds (width 16, fire-and-forget) so the HBM pipe holds a full
// burst per block while phases A/C/C2 run; phase D is then all-LDS.
// This attacks the measured MLP bound (R5-R7: 0.9-1.3 TB/s achieved BW).
// MODE 0: per-block partials; MODE 1: atomic fallback.
// NOTE: no min-waves arg — a VGPR cap caused 130 MB of scratch spills in R3.
template <int MODE>
__launch_bounds__(256)
__global__ void nurbs_loss_kernel(const float* __restrict__ ctrl_pred,
                                  const float* __restrict__ ctrl_gt,
                                  const float* __restrict__ mask,
                                  const float* __restrict__ xyz,
                                  double* __restrict__ pd, int G,
                                  int* __restrict__ badp)
{
    const int bb  = blockIdx.x;
    const int s   = bb >> 1;            // sample
    const int h   = bb & 1;             // u-half
    const int tid = threadIdx.x;

    __shared__ __align__(16) float s_xyz[32 * OUT_VC * 3];   // 24 KB, prefetched half-tile
    __shared__ __align__(16) float s_tmp[32 * MV_MAXC * 3];  // 12 KB [lu][j][d]
    __shared__ float s_Bu4[4 * 32];                  // SoA [r][lu]
    __shared__ float s_Bv4[4 * OUT_VC];              // SoA [r][v], pre-divided by sumBv
    __shared__ int   s_uoff[32];
    __shared__ int   s_voff[OUT_VC];
    __shared__ float s_invSumBu[32];
    __shared__ int   s_rowany[MU_MAXC];
    __shared__ int   s_colany[MV_MAXC];
    __shared__ int   s_mu, s_mv, s_bad;
    __shared__ float s_wred[4], s_wred2[4];
    __shared__ float s_ctrl_diff, s_ctrl_mask;

    if (tid < 32) { s_rowany[tid] = 0; s_colany[tid] = 0; }
    if (tid == 0) s_bad = 0;

    // ---- Phase A register loads FIRST (so their vmcnt wait doesn't include
    //      the prefetch), then the xyz bulk prefetch, then phase A compute ----
    const float4 mm = ((const float4*)(mask + (size_t)s * 1024))[tid];
    float4 pa, pb, pc, ga, gb, gc;
    const int mine = ((tid >> 7) == h);
    if (mine) {
        const float4* p4 = (const float4*)(ctrl_pred + (size_t)s * 3072);
        const float4* g4 = (const float4*)(ctrl_gt   + (size_t)s * 3072);
        pa = p4[3 * tid + 0]; pb = p4[3 * tid + 1]; pc = p4[3 * tid + 2];
        ga = g4[3 * tid + 0]; gb = g4[3 * tid + 1]; gc = g4[3 * tid + 2];
    }

    // ---- xyz half-tile -> LDS, 6 x 16B per thread, fire-and-forget.
    //      Per wave: lds dest = wave-uniform base + lane*16 (HW requirement). ----
    {
        const float* xsrc = xyz + ((size_t)s * 4096 + (size_t)h * 2048) * 3;
        #pragma unroll
        for (int w = 0; w < 6; w++) {
            const int f4 = tid + 256 * w;             // float4 index < 1536
            __builtin_amdgcn_global_load_lds(
                (const __attribute__((address_space(1))) unsigned int*)(xsrc + f4 * 4),
                (__attribute__((address_space(3))) unsigned int*)(s_xyz + f4 * 4),
                16, 0, 0);
        }
    }
    __syncthreads();   // covers the tid<32 init (prefetch drain here is harmless)

    // ---- Phase A compute: full-sample mask scan + half-sample masked MSE ----
    float lsum_mask = mm.x + mm.y + mm.z + mm.w;
    float lsum_diff = 0.f;
    {
        const int row = tid >> 3;
        const int colb = (tid & 7) * 4;
        if (lsum_mask > 0.f) s_rowany[row] = 1;
        if (mm.x > 0.f) s_colany[colb + 0] = 1;
        if (mm.y > 0.f) s_colany[colb + 1] = 1;
        if (mm.z > 0.f) s_colany[colb + 2] = 1;
        if (mm.w > 0.f) s_colany[colb + 3] = 1;
    }
    if (mine) {
        const float a0 = pa.x - ga.x, a1 = pa.y - ga.y, a2 = pa.z - ga.z;   // cell 0
        const float b0 = pa.w - ga.w, b1 = pb.x - gb.x, b2 = pb.y - gb.y;   // cell 1
        const float c0 = pb.z - gb.z, c1 = pb.w - gb.w, c2 = pc.x - gc.x;   // cell 2
        const float e0 = pc.y - gc.y, e1 = pc.z - gc.z, e2 = pc.w - gc.w;   // cell 3
        lsum_diff = mm.x * (a0 * a0 + a1 * a1 + a2 * a2)
                  + mm.y * (b0 * b0 + b1 * b1 + b2 * b2)
                  + mm.z * (c0 * c0 + c1 * c1 + c2 * c2)
                  + mm.w * (e0 * e0 + e1 * e1 + e2 * e2);
    }
    // halve the full-sample mask sum so sibling blocks sum to 1x
    lsum_mask *= 0.5f;
    #pragma unroll
    for (int off = 32; off > 0; off >>= 1) {
        lsum_mask += __shfl_down(lsum_mask, off);
        lsum_diff += __shfl_down(lsum_diff, off);
    }
    if ((tid & 63) == 0) { s_wred[tid >> 6] = lsum_mask; s_wred2[tid >> 6] = lsum_diff; }
    __syncthreads();

    if (tid == 0) {
        int cu = 0, cv = 0;
        #pragma unroll
        for (int i = 0; i < 32; i++) { cu += s_rowany[i]; cv += s_colany[i]; }
        s_mu = cu > (DEG + 1) ? cu : (DEG + 1);
        s_mv = cv > (DEG + 1) ? cv : (DEG + 1);
        s_ctrl_mask = s_wred[0] + s_wred[1] + s_wred[2] + s_wred[3];
        s_ctrl_diff = s_wred2[0] + s_wred2[1] + s_wred2[2] + s_wred2[3];
    }
    __syncthreads();

    // ---- Phase C: span-based Cox-de Boor, knots on-the-fly.
    //      threads 0..63: v-basis (all v); threads 64..95: u-basis (our 32 u) ----
    if (tid < 96) {
        const bool isV = tid < 64;
        const int t = isV ? tid : (tid - 64);
        const int gidx = isV ? t : (32 * h + t);
        const int L = (isV ? s_mv : s_mu) + DEG + 1;
        const float step = (1.f - 2.f * EPSV) / 63.f;
        const float uu = (gidx == 63) ? (1.f - EPSV) : (EPSV + step * (float)gidx);

        int span = DEG;
        #pragma unroll
        for (int k = DEG + 1; k < NKNOT - 1; k++)
            if (kv_at(k, L) <= uu) span = k;

        float left[DEG + 1], right[DEG + 1];
        #pragma unroll
        for (int j = 1; j <= DEG; j++) {
            left[j]  = uu - kv_at(span + 1 - j, L);
            right[j] = kv_at(span + j, L) - uu;
        }
        float N4[DEG + 1];
        N4[0] = 1.f;
        #pragma unroll
        for (int j = 1; j <= DEG; j++) {
            float saved = 0.f;
            #pragma unroll
            for (int r = 0; r < j; r++) {
                const float temp = N4[r] / (right[r + 1] + left[j - r]);
                N4[r] = saved + right[r + 1] * temp;
                saved = left[j - r] * temp;
            }
            N4[j] = saved;
        }
        const float sum = N4[0] + N4[1] + N4[2] + N4[3];
        const float invs = 1.0f / sum;
        const int off = span - DEG;                   // in [0, 28]
        if (isV) {
            #pragma unroll
            for (int r = 0; r < 4; r++) s_Bv4[r * 64 + t] = N4[r] * invs;  // fold 1/sumBv
            s_voff[t] = off;
        } else {
            #pragma unroll
            for (int r = 0; r < 4; r++) s_Bu4[r * 32 + t] = N4[r];
            s_uoff[t] = off; s_invSumBu[t] = invs;
        }
    }
    __syncthreads();

    // ---- Phase C2 (float4, ctrl from global/L2-hot): 768 float4 / 256 thr ----
    {
        const float4* ctrl4 = (const float4*)(ctrl_pred + (size_t)s * 3072);
        float4* tmp4 = (float4*)s_tmp;
        #pragma unroll
        for (int k = 0; k < 3; k++) {
            const int flat4 = tid + 256 * k;          // < 768
            const int lu = flat4 / 24;
            const int q = flat4 - lu * 24;
            const int off = s_uoff[lu];
            const float w0 = s_Bu4[0 * 32 + lu];
            const float w1 = s_Bu4[1 * 32 + lu];
            const float w2 = s_Bu4[2 * 32 + lu];
            const float w3 = s_Bu4[3 * 32 + lu];
            const float4 c0 = ctrl4[(off + 0) * 24 + q];
            const float4 c1 = ctrl4[(off + 1) * 24 + q];
            const float4 c2 = ctrl4[(off + 2) * 24 + q];
            const float4 c3 = ctrl4[(off + 3) * 24 + q];
            float4 a;
            a.x = w0 * c0.x + w1 * c1.x + w2 * c2.x + w3 * c3.x;
            a.y = w0 * c0.y + w1 * c1.y + w2 * c2.y + w3 * c3.y;
            a.z = w0 * c0.z + w1 * c1.z + w2 * c2.z + w3 * c3.z;
            a.w = w0 * c0.w + w1 * c1.w + w2 * c2.w + w3 * c3.w;
            tmp4[flat4] = a;
        }
    }
    __syncthreads();   // compiler's vmcnt(0) here also guarantees xyz prefetch landed

    // ---- Phase D: all-LDS. 2048 points / 256 thr = 8 each (4 v x 2 u) ----
    float lsum_surf = 0.f;
    int bad = 0;
    {
        const int vg   = (tid & 15) * 4;
        const int lug0 = tid >> 4;                    // 0..15
        float w[4][4]; int vo[4];
        #pragma unroll
        for (int c = 0; c < 4; c++) {
            vo[c] = s_voff[vg + c] * 3;
            #pragma unroll
            for (int r = 0; r < 4; r++) w[c][r] = s_Bv4[r * 64 + vg + c];
        }
        #pragma unroll
        for (int k = 0; k < 2; k++) {
            const int lu = lug0 + 16 * k;
            const float inv = s_invSumBu[lu];
            const float* tp = &s_tmp[lu * 96];
            const float4* x4 = (const float4*)(s_xyz + (lu * 64 + vg) * 3);
            const float4 xa = x4[0], xb = x4[1], xc = x4[2];
            float px[4], py[4], pz[4];
            px[0] = xa.x; py[0] = xa.y; pz[0] = xa.z;
            px[1] = xa.w; py[1] = xb.x; pz[1] = xb.y;
            px[2] = xb.z; py[2] = xb.w; pz[2] = xc.x;
            px[3] = xc.y; py[3] = xc.z; pz[3] = xc.w;
            #pragma unroll
            for (int c = 0; c < 4; c++) {
                const float* tpc = tp + vo[c];
                const float n0 = w[c][0] * tpc[0] + w[c][1] * tpc[3] + w[c][2] * tpc[6] + w[c][3] * tpc[9];
                const float n1 = w[c][0] * tpc[1] + w[c][1] * tpc[4] + w[c][2] * tpc[7] + w[c][3] * tpc[10];
                const float n2 = w[c][0] * tpc[2] + w[c][1] * tpc[5] + w[c][2] * tpc[8] + w[c][3] * tpc[11];
                const float x0 = n0 * inv, x1 = n1 * inv, x2 = n2 * inv;
                const float d0 = x0 - px[c];
                const float d1 = x1 - py[c];
                const float d2 = x2 - pz[c];
                lsum_surf += d0 * d0 + d1 * d1 + d2 * d2;
                if (!isfinite(x0) || !isfinite(x1) || !isfinite(x2)) bad = 1;
            }
        }
    }
    #pragma unroll
    for (int off = 32; off > 0; off >>= 1)
        lsum_surf += __shfl_down(lsum_surf, off);
    if ((tid & 63) == 0) s_wred[tid >> 6] = lsum_surf;
    if (bad) atomicOr(&s_bad, 1);
    __syncthreads();

    if (tid == 0) {
        const double surf = (double)s_wred[0] + s_wred[1] + s_wred[2] + s_wred[3];
        if (MODE == 0) {
            pd[bb]          = (double)s_ctrl_diff;
            pd[G + bb]      = (double)s_ctrl_mask;
            pd[2 * G + bb]  = surf;
            badp[bb]        = s_bad;
        } else {
            atomicAdd(&pd[0], (double)s_ctrl_diff);
            atomicAdd(&pd[1], (double)s_ctrl_mask);
            atomicAdd(&pd[2], surf);
            if (s_bad) atomicOr(badp, 1);
        }
    }
}

__global__ void finalize_partials_kernel(const double* __restrict__ pd,
                                         const int* __restrict__ badp,
                                         float* __restrict__ out, int G, int Bcnt)
{
    __shared__ double sd0[4], sd1[4], sd2[4];
    __shared__ int sb[4];
    const int tid = threadIdx.x;
    double a0 = 0.0, a1 = 0.0, a2 = 0.0; int bad = 0;
    for (int i = tid; i < G; i += 256) {
        a0 += pd[i]; a1 += pd[G + i]; a2 += pd[2 * G + i];
        bad |= badp[i];
    }
    #pragma unroll
    for (int off = 32; off > 0; off >>= 1) {
        a0 += __shfl_down(a0, off);
        a1 += __shfl_down(a1, off);
        a2 += __shfl_down(a2, off);
        bad |= __shfl_down(bad, off);
    }
    if ((tid & 63) == 0) { const int w = tid >> 6; sd0[w] = a0; sd1[w] = a1; sd2[w] = a2; sb[w] = bad; }
    __syncthreads();
    if (tid == 0) {
        double d0 = 0, d1 = 0, d2 = 0; int bb = 0;
        #pragma unroll
        for (int i = 0; i < 4; i++) { d0 += sd0[i]; d1 += sd1[i]; d2 += sd2[i]; bb |= sb[i]; }
        const double denc = d1 * 3.0;
        const double lc = d0 / (denc > 1.0 ? denc : 1.0);
        const double ls = d2 / ((double)Bcnt * OUT_UC * OUT_VC * 3.0);
        out[0] = (float)(lc + ls);            // total (pre-nan-guard, per ref)
        out[1] = (float)lc;                   // loss_ctrl
        out[2] = bb ? 1.0e6f : (float)ls;     // surf_mse with nan/inf guard
    }
}

__global__ void finalize_atomic_kernel(const double* __restrict__ acc,
                                       const int* __restrict__ bad,
                                       float* __restrict__ out, int Bcnt)
{
    const double denc = acc[1] * 3.0;
    const double lc = acc[0] / (denc > 1.0 ? denc : 1.0);
    const double ls = acc[2] / ((double)Bcnt * OUT_UC * OUT_VC * 3.0);
    out[0] = (float)(lc + ls);
    out[1] = (float)lc;
    out[2] = bad[0] ? 1.0e6f : (float)ls;
}

extern "C" void kernel_launch(void* const* d_in, const int* in_sizes, int n_in,
                              void* d_out, int out_size, void* d_ws, size_t ws_size,
                              hipStream_t stream)
{
    const float* pred = (const float*)d_in[0];
    const float* gt   = (const float*)d_in[1];
    const float* mask = (const float*)d_in[2];
    const float* xyz  = (const float*)d_in[3];
    const int Bcnt = in_sizes[2] / (MU_MAXC * MV_MAXC);   // 1024
    const int G = 2 * Bcnt;                               // half-sample blocks

    double* pd = (double*)d_ws;
    float* out = (float*)d_out;

    const size_t need = (size_t)3 * G * sizeof(double) + (size_t)G * sizeof(int);
    if (ws_size >= need) {
        int* badp = (int*)(pd + 3 * G);
        hipLaunchKernelGGL((nurbs_loss_kernel<0>), dim3(G), dim3(256), 0, stream,
                           pred, gt, mask, xyz, pd, G, badp);
        hipLaunchKernelGGL(finalize_partials_kernel, dim3(1), dim3(256), 0, stream,
                           pd, badp, out, G, Bcnt);
    } else {
        int* badp = (int*)(pd + 3);
        hipLaunchKernelGGL(zero_ws_kernel, dim3(1), dim3(1), 0, stream, pd, badp);
        hipLaunchKernelGGL((nurbs_loss_kernel<1>), dim3(G), dim3(256), 0, stream,
                           pred, gt, mask, xyz, pd, G, badp);
        hipLaunchKernelGGL(finalize_atomic_kernel, dim3(1), dim3(1), 0, stream,
                           pd, badp, out, Bcnt);
    }
}

// Round 10
// 113.360 us; speedup vs baseline: 1.0573x; 1.0573x over previous
//
#include <hip/hip_runtime.h>
#include <math.h>

#define MU_MAXC 32
#define MV_MAXC 32
#define OUT_UC  64
#define OUT_VC  64
#define DEG     3
#define NKNOT   (MU_MAXC + DEG + 1)   // 36
#define EPSV    1e-5f

__global__ void zero_ws_kernel(double* acc, int* bad) {
    acc[0] = 0.0; acc[1] = 0.0; acc[2] = 0.0; bad[0] = 0;
}

// Clamped open-uniform knot value (padded k >= L-1-DEG clamps to 1.0).
__device__ __forceinline__ float kv_at(int k, int L) {
    return (k <= DEG) ? 0.f : ((k >= L - 1 - DEG) ? 1.f : (float)k / (float)(L - 1));
}

#define TROW 33   // float4 stride of one padded tmp row (32 data quads + 1 pad)

// One block per sample. Instruction-count-optimized (kernel appears DVFS
// clock-limited ~1 GHz: VALUBusy*dur matches op count at ~0.9-1 GHz, so
// cycles, not latency, are the currency):
//  - tmp stored as [u][j][4] padded quads, row stride 33 quads -> phase D
//    reads 4 ds_read_b128/point (was 12 ds_read_b32)
//  - Bv weights [v][4] -> 1 b128/v;  C2 writes aligned j-quads (b128)
//  - isfinite hoisted to one check of the thread partial (propagation proof:
//    squares are +Inf/NaN and never cancel back to finite)
//  - mu/mv via ballots (no LDS flag arrays, no tid0 serial loop, one less sync)
// MODE 0: per-block partials; MODE 1: atomic fallback.
// NOTE: no min-waves arg — a VGPR cap caused 130 MB of scratch spills in R3.
template <int MODE>
__launch_bounds__(256)
__global__ void nurbs_loss_kernel(const float* __restrict__ ctrl_pred,
                                  const float* __restrict__ ctrl_gt,
                                  const float* __restrict__ mask,
                                  const float* __restrict__ xyz,
                                  double* __restrict__ pd, int Bcnt,
                                  int* __restrict__ badp)
{
    const int b   = blockIdx.x;
    const int tid = threadIdx.x;

    __shared__ __align__(16) float s_tmp[OUT_UC * TROW * 4]; // 33 KB padded quads
    __shared__ __align__(16) float s_Bv4[OUT_VC * 4];        // [v][r], /sumBv folded
    __shared__ float s_Bu4[4 * OUT_UC];                      // SoA [r][u]
    __shared__ int   s_uoff[OUT_UC];
    __shared__ int   s_voff[OUT_VC];
    __shared__ float s_invSumBu[OUT_UC];
    __shared__ int   s_mu, s_mv, s_bad;
    __shared__ float s_wred[4], s_wred2[4];
    __shared__ int   s_rowcnt[4];
    __shared__ unsigned int s_colmask[4];
    __shared__ float s_ctrl_diff, s_ctrl_mask;

    if (tid == 0) s_bad = 0;

    // ---- Phase A: masked ctrl MSE + mask sum + mu/mv via ballots.
    //      Thread t owns cells 4t..4t+3 (row = t>>3; 8 rows per wave, disjoint
    //      across waves; cols = (t&7)*4 + comp). ----
    float lsum_mask, lsum_diff;
    unsigned long long bx, by, bz, bw;
    {
        const float4 mm = ((const float4*)(mask + (size_t)b * 1024))[tid];
        const float4* p4 = (const float4*)(ctrl_pred + (size_t)b * 3072);
        const float4* g4 = (const float4*)(ctrl_gt   + (size_t)b * 3072);
        const float4 pa = p4[3 * tid + 0], pb = p4[3 * tid + 1], pc = p4[3 * tid + 2];
        const float4 ga = g4[3 * tid + 0], gb = g4[3 * tid + 1], gc = g4[3 * tid + 2];
        const float a0 = pa.x - ga.x, a1 = pa.y - ga.y, a2 = pa.z - ga.z;   // cell 0
        const float b0 = pa.w - ga.w, b1 = pb.x - gb.x, b2 = pb.y - gb.y;   // cell 1
        const float c0 = pb.z - gb.z, c1 = pb.w - gb.w, c2 = pc.x - gc.x;   // cell 2
        const float e0 = pc.y - gc.y, e1 = pc.z - gc.z, e2 = pc.w - gc.w;   // cell 3
        lsum_mask = mm.x + mm.y + mm.z + mm.w;
        lsum_diff = mm.x * (a0 * a0 + a1 * a1 + a2 * a2)
                  + mm.y * (b0 * b0 + b1 * b1 + b2 * b2)
                  + mm.z * (c0 * c0 + c1 * c1 + c2 * c2)
                  + mm.w * (e0 * e0 + e1 * e1 + e2 * e2);
        bx = __ballot(mm.x > 0.f);
        by = __ballot(mm.y > 0.f);
        bz = __ballot(mm.z > 0.f);
        bw = __ballot(mm.w > 0.f);
    }
    // rows-any count for this wave: byte r of (bx|by|bz|bw) nonzero
    int rowcnt;
    {
        unsigned long long anyb = bx | by | bz | bw;
        unsigned long long t = anyb | (anyb >> 4); t |= t >> 2; t |= t >> 1;
        rowcnt = __popcll(t & 0x0101010101010101ULL);
    }
    // col j any (this wave): lanes with lane&7 == j>>2 contribute comp j&3
    bool colany = false;
    {
        const int j = tid & 63;
        if (j < 32) {
            const int comp = j & 3;
            const unsigned long long sel = (comp == 0) ? bx : (comp == 1) ? by
                                          : (comp == 2) ? bz : bw;
            colany = (sel & (0x0101010101010101ULL << (j >> 2))) != 0ULL;
        }
    }
    const unsigned long long cmask = __ballot(colany);   // low 32 bits valid
    #pragma unroll
    for (int off = 32; off > 0; off >>= 1) {
        lsum_mask += __shfl_down(lsum_mask, off);
        lsum_diff += __shfl_down(lsum_diff, off);
    }
    if ((tid & 63) == 0) {
        const int w = tid >> 6;
        s_wred[w] = lsum_mask; s_wred2[w] = lsum_diff;
        s_rowcnt[w] = rowcnt;  s_colmask[w] = (unsigned int)cmask;
    }
    __syncthreads();

    if (tid == 0) {
        const int cu = s_rowcnt[0] + s_rowcnt[1] + s_rowcnt[2] + s_rowcnt[3];
        const int cv = __popc(s_colmask[0] | s_colmask[1] | s_colmask[2] | s_colmask[3]);
        s_mu = cu > (DEG + 1) ? cu : (DEG + 1);
        s_mv = cv > (DEG + 1) ? cv : (DEG + 1);
        s_ctrl_mask = s_wred[0] + s_wred[1] + s_wred[2] + s_wred[3];
        s_ctrl_diff = s_wred2[0] + s_wred2[1] + s_wred2[2] + s_wred2[3];
    }
    __syncthreads();

    // ---- Phase C: span-based Cox-de Boor, knots on-the-fly ----
    if (tid < 128) {
        const bool isU = tid < 64;
        const int t = isU ? tid : (tid - 64);
        const int L = (isU ? s_mu : s_mv) + DEG + 1;
        const float step = (1.f - 2.f * EPSV) / 63.f;
        const float uu = (t == 63) ? (1.f - EPSV) : (EPSV + step * (float)t);

        int span = DEG;
        #pragma unroll
        for (int k = DEG + 1; k < NKNOT - 1; k++)
            if (kv_at(k, L) <= uu) span = k;

        float left[DEG + 1], right[DEG + 1];
        #pragma unroll
        for (int j = 1; j <= DEG; j++) {
            left[j]  = uu - kv_at(span + 1 - j, L);
            right[j] = kv_at(span + j, L) - uu;
        }
        float N4[DEG + 1];
        N4[0] = 1.f;
        #pragma unroll
        for (int j = 1; j <= DEG; j++) {
            float saved = 0.f;
            #pragma unroll
            for (int r = 0; r < j; r++) {
                const float temp = N4[r] / (right[r + 1] + left[j - r]);
                N4[r] = saved + right[r + 1] * temp;
                saved = left[j - r] * temp;
            }
            N4[j] = saved;
        }
        const float sum = N4[0] + N4[1] + N4[2] + N4[3];
        const float invs = 1.0f / sum;
        const int off = span - DEG;                   // in [0, 28]
        if (isU) {
            #pragma unroll
            for (int r = 0; r < 4; r++) s_Bu4[r * 64 + t] = N4[r];
            s_uoff[t] = off; s_invSumBu[t] = invs;
        } else {
            ((float4*)s_Bv4)[t] = make_float4(N4[0] * invs, N4[1] * invs,
                                              N4[2] * invs, N4[3] * invs);
            s_voff[t] = off;
        }
    }
    __syncthreads();

    // ---- Phase C2: 512 tasks (u, j-quad m<8), 2 per thread.
    //      Each task: 12 float4 ctrl reads (L2-hot), 12 MACs x4, 4 b128 writes
    //      of padded quads (d0,d1,d2,0) at quad index u*TROW + 4m + i. ----
    {
        const float4* ctrl4 = (const float4*)(ctrl_pred + (size_t)b * 3072);
        #pragma unroll
        for (int z = 0; z < 2; z++) {
            const int task = tid + 256 * z;           // < 512
            const int u = task >> 3;
            const int m = task & 7;
            const int off = s_uoff[u];
            const float w0 = s_Bu4[0 * 64 + u];
            const float w1 = s_Bu4[1 * 64 + u];
            const float w2 = s_Bu4[2 * 64 + u];
            const float w3 = s_Bu4[3 * 64 + u];
            float f[12];
            #pragma unroll
            for (int e = 0; e < 3; e++) {
                const float4 c0 = ctrl4[(off + 0) * 24 + m * 3 + e];
                const float4 c1 = ctrl4[(off + 1) * 24 + m * 3 + e];
                const float4 c2 = ctrl4[(off + 2) * 24 + m * 3 + e];
                const float4 c3 = ctrl4[(off + 3) * 24 + m * 3 + e];
                f[e * 4 + 0] = w0 * c0.x + w1 * c1.x + w2 * c2.x + w3 * c3.x;
                f[e * 4 + 1] = w0 * c0.y + w1 * c1.y + w2 * c2.y + w3 * c3.y;
                f[e * 4 + 2] = w0 * c0.z + w1 * c1.z + w2 * c2.z + w3 * c3.z;
                f[e * 4 + 3] = w0 * c0.w + w1 * c1.w + w2 * c2.w + w3 * c3.w;
            }
            float4* dst = ((float4*)s_tmp) + (u * TROW + m * 4);
            dst[0] = make_float4(f[0], f[1],  f[2],  0.f);
            dst[1] = make_float4(f[3], f[4],  f[5],  0.f);
            dst[2] = make_float4(f[6], f[7],  f[8],  0.f);
            dst[3] = make_float4(f[9], f[10], f[11], 0.f);
        }
    }
    __syncthreads();

    // ---- Phase D: 16 points/thread (4 consecutive v x 4 u).
    //      Per point: 4 ds_read_b128 (padded quads) + 12 MAC; xyz via 3 b128. ----
    float lsum_surf = 0.f;
    {
        const int vg  = (tid & 15) * 4;
        const int ug0 = tid >> 4;                     // 0..15
        float4 wv[4]; int vo[4];
        #pragma unroll
        for (int c = 0; c < 4; c++) {
            vo[c] = s_voff[vg + c];
            wv[c] = ((const float4*)s_Bv4)[vg + c];
        }
        #pragma unroll
        for (int k = 0; k < 4; k++) {
            const int u = ug0 + 16 * k;
            const float inv = s_invSumBu[u];
            const float4* trow = ((const float4*)s_tmp) + u * TROW;
            const float4* x4 = (const float4*)(xyz + ((size_t)b * 4096 + u * 64 + vg) * 3);
            const float4 xa = x4[0], xb = x4[1], xc = x4[2];
            const float px[4] = {xa.x, xa.w, xb.z, xc.y};
            const float py[4] = {xa.y, xb.x, xb.w, xc.z};
            const float pz[4] = {xa.z, xb.y, xc.x, xc.w};
            #pragma unroll
            for (int c = 0; c < 4; c++) {
                const float4 t0 = trow[vo[c] + 0];
                const float4 t1 = trow[vo[c] + 1];
                const float4 t2 = trow[vo[c] + 2];
                const float4 t3 = trow[vo[c] + 3];
                const float4 w = wv[c];
                const float n0 = w.x * t0.x + w.y * t1.x + w.z * t2.x + w.w * t3.x;
                const float n1 = w.x * t0.y + w.y * t1.y + w.z * t2.y + w.w * t3.y;
                const float n2 = w.x * t0.z + w.y * t1.z + w.z * t2.z + w.w * t3.z;
                const float x0 = n0 * inv, x1 = n1 * inv, x2 = n2 * inv;
                const float d0 = x0 - px[c];
                const float d1 = x1 - py[c];
                const float d2 = x2 - pz[c];
                lsum_surf += d0 * d0 + d1 * d1 + d2 * d2;
            }
        }
    }
    // hoisted non-finite check: any non-finite x makes the partial +Inf/NaN
    const int bad = !isfinite(lsum_surf);
    #pragma unroll
    for (int off = 32; off > 0; off >>= 1)
        lsum_surf += __shfl_down(lsum_surf, off);
    if ((tid & 63) == 0) s_wred[tid >> 6] = lsum_surf;
    if (bad) atomicOr(&s_bad, 1);
    __syncthreads();

    if (tid == 0) {
        const double surf = (double)s_wred[0] + s_wred[1] + s_wred[2] + s_wred[3];
        if (MODE == 0) {
            pd[b]             = (double)s_ctrl_diff;
            pd[Bcnt + b]      = (double)s_ctrl_mask;
            pd[2 * Bcnt + b]  = surf;
            badp[b]           = s_bad;
        } else {
            atomicAdd(&pd[0], (double)s_ctrl_diff);
            atomicAdd(&pd[1], (double)s_ctrl_mask);
            atomicAdd(&pd[2], surf);
            if (s_bad) atomicOr(badp, 1);
        }
    }
}

__global__ void finalize_partials_kernel(const double* __restrict__ pd,
                                         const int* __restrict__ badp,
                                         float* __restrict__ out, int Bcnt)
{
    __shared__ double sd0[4], sd1[4], sd2[4];
    __shared__ int sb[4];
    const int tid = threadIdx.x;
    double a0 = 0.0, a1 = 0.0, a2 = 0.0; int bad = 0;
    for (int i = tid; i < Bcnt; i += 256) {
        a0 += pd[i]; a1 += pd[Bcnt + i]; a2 += pd[2 * Bcnt + i];
        bad |= badp[i];
    }
    #pragma unroll
    for (int off = 32; off > 0; off >>= 1) {
        a0 += __shfl_down(a0, off);
        a1 += __shfl_down(a1, off);
        a2 += __shfl_down(a2, off);
        bad |= __shfl_down(bad, off);
    }
    if ((tid & 63) == 0) { const int w = tid >> 6; sd0[w] = a0; sd1[w] = a1; sd2[w] = a2; sb[w] = bad; }
    __syncthreads();
    if (tid == 0) {
        double d0 = 0, d1 = 0, d2 = 0; int bb = 0;
        #pragma unroll
        for (int i = 0; i < 4; i++) { d0 += sd0[i]; d1 += sd1[i]; d2 += sd2[i]; bb |= sb[i]; }
        const double denc = d1 * 3.0;
        const double lc = d0 / (denc > 1.0 ? denc : 1.0);
        const double ls = d2 / ((double)Bcnt * OUT_UC * OUT_VC * 3.0);
        out[0] = (float)(lc + ls);            // total (pre-nan-guard, per ref)
        out[1] = (float)lc;                   // loss_ctrl
        out[2] = bb ? 1.0e6f : (float)ls;     // surf_mse with nan/inf guard
    }
}

__global__ void finalize_atomic_kernel(const double* __restrict__ acc,
                                       const int* __restrict__ bad,
                                       float* __restrict__ out, int Bcnt)
{
    const double denc = acc[1] * 3.0;
    const double lc = acc[0] / (denc > 1.0 ? denc : 1.0);
    const double ls = acc[2] / ((double)Bcnt * OUT_UC * OUT_VC * 3.0);
    out[0] = (float)(lc + ls);
    out[1] = (float)lc;
    out[2] = bad[0] ? 1.0e6f : (float)ls;
}

extern "C" void kernel_launch(void* const* d_in, const int* in_sizes, int n_in,
                              void* d_out, int out_size, void* d_ws, size_t ws_size,
                              hipStream_t stream)
{
    const float* pred = (const float*)d_in[0];
    const float* gt   = (const float*)d_in[1];
    const float* mask = (const float*)d_in[2];
    const float* xyz  = (const float*)d_in[3];
    const int Bcnt = in_sizes[2] / (MU_MAXC * MV_MAXC);   // 1024

    double* pd = (double*)d_ws;
    float* out = (float*)d_out;

    const size_t need = (size_t)3 * Bcnt * sizeof(double) + (size_t)Bcnt * sizeof(int);
    if (ws_size >= need) {
        int* badp = (int*)(pd + 3 * Bcnt);
        hipLaunchKernelGGL((nurbs_loss_kernel<0>), dim3(Bcnt), dim3(256), 0, stream,
                           pred, gt, mask, xyz, pd, Bcnt, badp);
        hipLaunchKernelGGL(finalize_partials_kernel, dim3(1), dim3(256), 0, stream,
                           pd, badp, out, Bcnt);
    } else {
        int* badp = (int*)(pd + 3);
        hipLaunchKernelGGL(zero_ws_kernel, dim3(1), dim3(1), 0, stream, pd, badp);
        hipLaunchKernelGGL((nurbs_loss_kernel<1>), dim3(Bcnt), dim3(256), 0, stream,
                           pred, gt, mask, xyz, pd, Bcnt, badp);
        hipLaunchKernelGGL(finalize_atomic_kernel, dim3(1), dim3(1), 0, stream,
                           pd, badp, out, Bcnt);
    }
}